// Round 2
// baseline (203.306 us; speedup 1.0000x reference)
//
#include <hip/hip_runtime.h>

#define V 32
#define B 128
#define P 256
#define J 75
#define NF 32
#define S2 25

// ---------------------------------------------------------------------------
// Kernel 1: transform + SLayer.  One block per (v,b); stage points in LDS;
// thread j (<75) accumulates sum_p m * exp(-d2).
// ---------------------------------------------------------------------------
__global__ __launch_bounds__(128) void slayer_kernel(
    const float* __restrict__ births,
    const float* __restrict__ lifetimes,
    const int* __restrict__ mask,
    const float* __restrict__ centers,
    const float* __restrict__ sharpness,
    float* __restrict__ z)                     // [V*B, J]
{
    const int vb = blockIdx.x;                 // v*B + b
    const int v  = vb >> 7;                    // / 128
    const int tid = threadIdx.x;

    __shared__ float qx[P], qy[P], qm[P];

    const float inv = 0.70710678118654752f;
    for (int p = tid; p < P; p += 128) {
        const int gi = vb * P + p;
        float b0 = births[gi];
        float l0 = lifetimes[gi];
        float d  = b0 + l0 + 0.01f;
        float x  = (b0 + d) * inv;
        float y  = (d - b0) * inv;
        if (y <= 0.1f) y = __logf(y * 10.0f) * 0.1f + 0.1f;
        qx[p] = x;
        qy[p] = y;
        qm[p] = (float)mask[gi];
    }
    __syncthreads();

    if (tid < J) {
        const int cj = (v * J + tid) * 2;
        float cx = centers[cj + 0];
        float cy = centers[cj + 1];
        float sx = sharpness[cj + 0];
        float sy = sharpness[cj + 1];
        float s2x = sx * sx, s2y = sy * sy;
        float acc = 0.f;
        #pragma unroll 4
        for (int p = 0; p < P; ++p) {
            float dx = qx[p] - cx;
            float dy = qy[p] - cy;
            float d2 = s2x * dx * dx + s2y * dy * dy;
            acc += qm[p] * __expf(-d2);
        }
        z[vb * J + tid] = acc;
    }
}

// ---------------------------------------------------------------------------
// Kernel 2: neighbor stack + stage_1 (two 1x1 convs, max over 8) + l1.
// One block per (v,b).
// ---------------------------------------------------------------------------
__global__ __launch_bounds__(128) void stage12_kernel(
    const float* __restrict__ z,               // [V*B, J]
    const float* __restrict__ w1,              // [V, NF, 3]
    const float* __restrict__ w2,              // [V, 8, NF]
    const float* __restrict__ l1_w,            // [V, S2, J]
    const float* __restrict__ l1_b,            // [V, S2]
    float* __restrict__ u_pre)                 // [V*B, S2]
{
    const int vb = blockIdx.x;
    const int v  = vb >> 7;
    const int b  = vb & 127;
    const int vm = (v + V - 1) & (V - 1);
    const int vp = (v + 1) & (V - 1);
    const int tid = threadIdx.x;

    __shared__ float z0[J], z1[J], z2[J];
    __shared__ float w1s[NF * 3];
    __shared__ float w2s[8 * NF];
    __shared__ float hsh[J];

    if (tid < J) {
        z0[tid] = z[(vm * B + b) * J + tid];
        z1[tid] = z[(v  * B + b) * J + tid];
        z2[tid] = z[(vp * B + b) * J + tid];
    }
    if (tid < NF * 3) w1s[tid] = w1[v * NF * 3 + tid];
    w2s[tid]       = w2[v * 8 * NF + tid];
    w2s[tid + 128] = w2[v * 8 * NF + tid + 128];
    __syncthreads();

    if (tid < J) {
        float a0 = z0[tid], a1 = z1[tid], a2 = z2[tid];
        float hf[NF];
        #pragma unroll
        for (int f = 0; f < NF; ++f)
            hf[f] = w1s[f * 3 + 0] * a0 + w1s[f * 3 + 1] * a1 + w1s[f * 3 + 2] * a2;
        float hm = -3.4e38f;
        #pragma unroll
        for (int g = 0; g < 8; ++g) {
            float s = 0.f;
            #pragma unroll
            for (int f = 0; f < NF; ++f) s += w2s[g * NF + f] * hf[f];
            hm = fmaxf(hm, s);
        }
        hsh[tid] = hm;
    }
    __syncthreads();

    if (tid < S2) {
        float acc = l1_b[v * S2 + tid];
        const float* wrow = l1_w + (v * S2 + tid) * J;
        for (int j = 0; j < J; ++j) acc += hsh[j] * wrow[j];
        u_pre[vb * S2 + tid] = acc;
    }
}

// ---------------------------------------------------------------------------
// Kernel 3: BN over batch axis (per v,o) + l2 + ReLU.  One block per v.
// Writes x TRANSPOSED: xT[(v*S2+p)*B + b] so fc1 reads coalesce.
// ---------------------------------------------------------------------------
__global__ __launch_bounds__(256) void bn1_l2_kernel(
    const float* __restrict__ u_pre,           // [V*B, S2]
    const float* __restrict__ bn1_g,
    const float* __restrict__ bn1_b,
    const float* __restrict__ l2_w,            // [V, S2, S2]
    const float* __restrict__ l2_b,            // [V, S2]
    float* __restrict__ xT)                    // [V*S2, B]
{
    const int v = blockIdx.x;
    const int tid = threadIdx.x;

    __shared__ float u[B * S2];
    __shared__ float w[S2 * S2];
    __shared__ float sc[S2], sh[S2];

    for (int i = tid; i < B * S2; i += 256) u[i] = u_pre[v * B * S2 + i];
    for (int i = tid; i < S2 * S2; i += 256) w[i] = l2_w[v * S2 * S2 + i];
    __syncthreads();

    if (tid < S2) {
        float s = 0.f, ss = 0.f;
        for (int b = 0; b < B; ++b) {
            float x = u[b * S2 + tid];
            s += x; ss += x * x;
        }
        float mean = s * (1.f / B);
        float var  = ss * (1.f / B) - mean * mean;
        float istd = rsqrtf(var + 1e-5f);
        float g  = bn1_g[v * S2 + tid];
        float be = bn1_b[v * S2 + tid];
        sc[tid] = g * istd;
        sh[tid] = be - mean * g * istd;
    }
    __syncthreads();

    for (int i = tid; i < B * S2; i += 256) {
        int o = i % S2;
        u[i] = u[i] * sc[o] + sh[o];
    }
    __syncthreads();

    for (int i = tid; i < B * S2; i += 256) {
        int b = i & 127;
        int p = i >> 7;
        float acc = l2_b[v * S2 + p];
        #pragma unroll
        for (int o = 0; o < S2; ++o) acc += u[b * S2 + o] * w[p * S2 + o];
        acc = fmaxf(acc, 0.f);
        xT[(v * S2 + p) * B + b] = acc;
    }
}

// ---------------------------------------------------------------------------
// Kernel 4: fc1 + BN over batch.  125 blocks x 4 neurons; thread = b.
// ---------------------------------------------------------------------------
#define FC1_TILE 4
__global__ __launch_bounds__(128) void fc1_bn2_kernel(
    const float* __restrict__ xT,              // [800, B]
    const float* __restrict__ fc1_w,           // [500, 800]
    const float* __restrict__ fc1_b,           // [500]
    const float* __restrict__ bn2_g,
    const float* __restrict__ bn2_b,
    float* __restrict__ y1n)                   // [500, B]
{
    const int n0 = blockIdx.x * FC1_TILE;
    const int tid = threadIdx.x;               // = b
    const int K = V * S2;                      // 800

    __shared__ float wsm[FC1_TILE][V * S2];
    __shared__ float red[2][2][FC1_TILE];

    for (int i = tid; i < FC1_TILE * K; i += 128) {
        int ni = i / K;
        int k  = i - ni * K;
        wsm[ni][k] = fc1_w[(n0 + ni) * K + k];
    }
    __syncthreads();

    float acc[FC1_TILE] = {0.f, 0.f, 0.f, 0.f};
    for (int k = 0; k < K; ++k) {
        float xv = xT[k * B + tid];
        #pragma unroll
        for (int ni = 0; ni < FC1_TILE; ++ni) acc[ni] += xv * wsm[ni][k];
    }

    const int wave = tid >> 6;
    const int lane = tid & 63;
    #pragma unroll
    for (int ni = 0; ni < FC1_TILE; ++ni) {
        acc[ni] += fc1_b[n0 + ni];
        float s = acc[ni], ss = acc[ni] * acc[ni];
        #pragma unroll
        for (int off = 32; off > 0; off >>= 1) {
            s  += __shfl_down(s,  off, 64);
            ss += __shfl_down(ss, off, 64);
        }
        if (lane == 0) { red[wave][0][ni] = s; red[wave][1][ni] = ss; }
    }
    __syncthreads();

    #pragma unroll
    for (int ni = 0; ni < FC1_TILE; ++ni) {
        float s  = red[0][0][ni] + red[1][0][ni];
        float ss = red[0][1][ni] + red[1][1][ni];
        float mean = s * (1.f / B);
        float var  = ss * (1.f / B) - mean * mean;
        float istd = rsqrtf(var + 1e-5f);
        float g  = bn2_g[n0 + ni];
        float be = bn2_b[n0 + ni];
        float scl = g * istd;
        y1n[(n0 + ni) * B + tid] = acc[ni] * scl + (be - mean * scl);
    }
}

// ---------------------------------------------------------------------------
// Kernel 5: fc2.  One block per output neuron k; thread = b.
// ---------------------------------------------------------------------------
__global__ __launch_bounds__(128) void fc2_kernel(
    const float* __restrict__ y1n,             // [500, B]
    const float* __restrict__ fc2_w,           // [200, 500]
    const float* __restrict__ fc2_b,           // [200]
    float* __restrict__ out)                   // [B, 200]
{
    const int k = blockIdx.x;
    const int tid = threadIdx.x;               // = b

    __shared__ float wsm[500];
    for (int i = tid; i < 500; i += 128) wsm[i] = fc2_w[k * 500 + i];
    __syncthreads();

    float acc = fc2_b[k];
    for (int n = 0; n < 500; ++n) acc += y1n[n * B + tid] * wsm[n];
    out[tid * 200 + k] = acc;
}

// ---------------------------------------------------------------------------
extern "C" void kernel_launch(void* const* d_in, const int* in_sizes, int n_in,
                              void* d_out, int out_size, void* d_ws, size_t ws_size,
                              hipStream_t stream) {
    const float* births    = (const float*)d_in[0];
    const float* lifetimes = (const float*)d_in[1];
    const int*   mask      = (const int*)d_in[2];
    const float* centers   = (const float*)d_in[3];
    const float* sharpness = (const float*)d_in[4];
    const float* w1        = (const float*)d_in[5];
    const float* w2        = (const float*)d_in[6];
    const float* l1_w      = (const float*)d_in[7];
    const float* l1_b      = (const float*)d_in[8];
    const float* bn1_g     = (const float*)d_in[9];
    const float* bn1_b     = (const float*)d_in[10];
    const float* l2_w      = (const float*)d_in[11];
    const float* l2_b      = (const float*)d_in[12];
    const float* fc1_w     = (const float*)d_in[13];
    const float* fc1_b     = (const float*)d_in[14];
    const float* bn2_g     = (const float*)d_in[15];
    const float* bn2_b     = (const float*)d_in[16];
    const float* fc2_w     = (const float*)d_in[17];
    const float* fc2_b     = (const float*)d_in[18];
    float* out = (float*)d_out;

    float* ws    = (float*)d_ws;
    float* z     = ws;                            // V*B*J   = 307200
    float* u_pre = ws + 307200;                   // V*B*S2  = 102400
    float* xT    = ws + 307200 + 102400;          // 800*B   = 102400
    float* y1n   = ws + 307200 + 102400 + 102400; // 500*B   = 64000

    slayer_kernel <<<V * B, 128, 0, stream>>>(births, lifetimes, mask, centers, sharpness, z);
    stage12_kernel<<<V * B, 128, 0, stream>>>(z, w1, w2, l1_w, l1_b, u_pre);
    bn1_l2_kernel <<<V, 256, 0, stream>>>(u_pre, bn1_g, bn1_b, l2_w, l2_b, xT);
    fc1_bn2_kernel<<<(500 / FC1_TILE), 128, 0, stream>>>(xT, fc1_w, fc1_b, bn2_g, bn2_b, y1n);
    fc2_kernel    <<<200, 128, 0, stream>>>(y1n, fc2_w, fc2_b, out);
}

// Round 3
// 183.205 us; speedup vs baseline: 1.1097x; 1.1097x over previous
//
#include <hip/hip_runtime.h>

#define V 32
#define B 128
#define P 256
#define J 75
#define NF 32
#define S2 25

// ---------------------------------------------------------------------------
// Kernel 1: transform + SLayer with mask compaction.
// One block per (v,b). Live points packed in LDS as float4(x, y, x^2, y^2);
// thread j (<75) evaluates sum_p exp(kc + k0*x2 + k1*y2 + k2*x + k3*y)
// (coefficients pre-negated — identical algebra to the reference's qa.ca).
// ---------------------------------------------------------------------------
__global__ __launch_bounds__(128) void slayer_kernel(
    const float* __restrict__ births,
    const float* __restrict__ lifetimes,
    const int* __restrict__ mask,
    const float* __restrict__ centers,
    const float* __restrict__ sharpness,
    float* __restrict__ z)                     // [V*B, J]
{
    const int vb = blockIdx.x;                 // v*B + b
    const int v  = vb >> 7;                    // / 128
    const int tid = threadIdx.x;
    const int lane = tid & 63;

    __shared__ float4 pts[P];
    __shared__ int cnt;

    if (tid == 0) cnt = 0;
    __syncthreads();

    const float inv = 0.70710678118654752f;
    #pragma unroll
    for (int c = 0; c < 2; ++c) {
        const int p  = tid + c * 128;
        const int gi = vb * P + p;
        float b0 = births[gi];
        float l0 = lifetimes[gi];
        int   m  = mask[gi];
        float d  = b0 + l0 + 0.01f;
        float x  = (b0 + d) * inv;
        float y  = (d - b0) * inv;
        if (y <= 0.1f) y = __logf(y * 10.0f) * 0.1f + 0.1f;

        bool keep = (m != 0);
        unsigned long long bal = __ballot(keep);
        unsigned long long lt  = (1ull << lane) - 1ull;
        int prefix = __popcll(bal & lt);
        int total  = __popcll(bal);
        int base = 0;
        if (lane == 0) base = atomicAdd(&cnt, total);
        base = __shfl(base, 0, 64);
        if (keep) pts[base + prefix] = make_float4(x, y, x * x, y * y);
    }
    __syncthreads();

    const int n = cnt;
    if (tid < J) {
        const int cj = (v * J + tid) * 2;
        float cx = centers[cj + 0];
        float cy = centers[cj + 1];
        float sx = sharpness[cj + 0];
        float sy = sharpness[cj + 1];
        float s2x = sx * sx, s2y = sy * sy;
        // pre-negated coefficients: argument to exp is already -d2
        float k0 = -s2x;
        float k1 = -s2y;
        float k2 = 2.0f * s2x * cx;
        float k3 = 2.0f * s2y * cy;
        float kc = -(s2x * cx * cx + s2y * cy * cy);
        float acc = 0.f;
        #pragma unroll 2
        for (int p = 0; p < n; ++p) {
            float4 a = pts[p];
            float d = fmaf(k0, a.z, kc);
            d = fmaf(k1, a.w, d);
            d = fmaf(k2, a.x, d);
            d = fmaf(k3, a.y, d);
            acc += __expf(d);
        }
        z[vb * J + tid] = acc;
    }
}

// ---------------------------------------------------------------------------
// Kernel 2: neighbor stack + stage_1 (two 1x1 convs, max over 8) + l1.
// One block per (v,b).
// ---------------------------------------------------------------------------
__global__ __launch_bounds__(128) void stage12_kernel(
    const float* __restrict__ z,               // [V*B, J]
    const float* __restrict__ w1,              // [V, NF, 3]
    const float* __restrict__ w2,              // [V, 8, NF]
    const float* __restrict__ l1_w,            // [V, S2, J]
    const float* __restrict__ l1_b,            // [V, S2]
    float* __restrict__ u_pre)                 // [V*B, S2]
{
    const int vb = blockIdx.x;
    const int v  = vb >> 7;
    const int b  = vb & 127;
    const int vm = (v + V - 1) & (V - 1);
    const int vp = (v + 1) & (V - 1);
    const int tid = threadIdx.x;

    __shared__ float z0[J], z1[J], z2[J];
    __shared__ float w1s[NF * 3];
    __shared__ float w2s[8 * NF];
    __shared__ float hsh[J];

    if (tid < J) {
        z0[tid] = z[(vm * B + b) * J + tid];
        z1[tid] = z[(v  * B + b) * J + tid];
        z2[tid] = z[(vp * B + b) * J + tid];
    }
    if (tid < NF * 3) w1s[tid] = w1[v * NF * 3 + tid];
    w2s[tid]       = w2[v * 8 * NF + tid];
    w2s[tid + 128] = w2[v * 8 * NF + tid + 128];
    __syncthreads();

    if (tid < J) {
        float a0 = z0[tid], a1 = z1[tid], a2 = z2[tid];
        float hf[NF];
        #pragma unroll
        for (int f = 0; f < NF; ++f)
            hf[f] = w1s[f * 3 + 0] * a0 + w1s[f * 3 + 1] * a1 + w1s[f * 3 + 2] * a2;
        float hm = -3.4e38f;
        #pragma unroll
        for (int g = 0; g < 8; ++g) {
            float s = 0.f;
            #pragma unroll
            for (int f = 0; f < NF; ++f) s += w2s[g * NF + f] * hf[f];
            hm = fmaxf(hm, s);
        }
        hsh[tid] = hm;
    }
    __syncthreads();

    if (tid < S2) {
        float acc = l1_b[v * S2 + tid];
        const float* wrow = l1_w + (v * S2 + tid) * J;
        for (int j = 0; j < J; ++j) acc += hsh[j] * wrow[j];
        u_pre[vb * S2 + tid] = acc;
    }
}

// ---------------------------------------------------------------------------
// Kernel 3: BN over batch axis (per v,o) + l2 + ReLU.  One block per v.
// Writes x TRANSPOSED: xT[(v*S2+p)*B + b] so fc1 reads coalesce.
// ---------------------------------------------------------------------------
__global__ __launch_bounds__(256) void bn1_l2_kernel(
    const float* __restrict__ u_pre,           // [V*B, S2]
    const float* __restrict__ bn1_g,
    const float* __restrict__ bn1_b,
    const float* __restrict__ l2_w,            // [V, S2, S2]
    const float* __restrict__ l2_b,            // [V, S2]
    float* __restrict__ xT)                    // [V*S2, B]
{
    const int v = blockIdx.x;
    const int tid = threadIdx.x;

    __shared__ float u[B * S2];
    __shared__ float w[S2 * S2];
    __shared__ float sc[S2], sh[S2];

    for (int i = tid; i < B * S2; i += 256) u[i] = u_pre[v * B * S2 + i];
    for (int i = tid; i < S2 * S2; i += 256) w[i] = l2_w[v * S2 * S2 + i];
    __syncthreads();

    if (tid < S2) {
        float s = 0.f, ss = 0.f;
        for (int b = 0; b < B; ++b) {
            float x = u[b * S2 + tid];
            s += x; ss += x * x;
        }
        float mean = s * (1.f / B);
        float var  = ss * (1.f / B) - mean * mean;
        float istd = rsqrtf(var + 1e-5f);
        float g  = bn1_g[v * S2 + tid];
        float be = bn1_b[v * S2 + tid];
        sc[tid] = g * istd;
        sh[tid] = be - mean * g * istd;
    }
    __syncthreads();

    for (int i = tid; i < B * S2; i += 256) {
        int o = i % S2;
        u[i] = u[i] * sc[o] + sh[o];
    }
    __syncthreads();

    for (int i = tid; i < B * S2; i += 256) {
        int b = i & 127;
        int p = i >> 7;
        float acc = l2_b[v * S2 + p];
        #pragma unroll
        for (int o = 0; o < S2; ++o) acc += u[b * S2 + o] * w[p * S2 + o];
        acc = fmaxf(acc, 0.f);
        xT[(v * S2 + p) * B + b] = acc;
    }
}

// ---------------------------------------------------------------------------
// Kernel 4: fc1 + BN over batch.  250 blocks x 2 neurons; thread = b.
// ---------------------------------------------------------------------------
#define FC1_TILE 2
__global__ __launch_bounds__(128) void fc1_bn2_kernel(
    const float* __restrict__ xT,              // [800, B]
    const float* __restrict__ fc1_w,           // [500, 800]
    const float* __restrict__ fc1_b,           // [500]
    const float* __restrict__ bn2_g,
    const float* __restrict__ bn2_b,
    float* __restrict__ y1n)                   // [500, B]
{
    const int n0 = blockIdx.x * FC1_TILE;
    const int tid = threadIdx.x;               // = b
    const int K = V * S2;                      // 800

    __shared__ float wsm[FC1_TILE][V * S2];
    __shared__ float red[2][2][FC1_TILE];

    for (int i = tid; i < FC1_TILE * K; i += 128) {
        int ni = i / K;
        int k  = i - ni * K;
        wsm[ni][k] = fc1_w[(n0 + ni) * K + k];
    }
    __syncthreads();

    float acc[FC1_TILE] = {0.f, 0.f};
    for (int k = 0; k < K; ++k) {
        float xv = xT[k * B + tid];
        #pragma unroll
        for (int ni = 0; ni < FC1_TILE; ++ni) acc[ni] += xv * wsm[ni][k];
    }

    const int wave = tid >> 6;
    const int lane = tid & 63;
    #pragma unroll
    for (int ni = 0; ni < FC1_TILE; ++ni) {
        acc[ni] += fc1_b[n0 + ni];
        float s = acc[ni], ss = acc[ni] * acc[ni];
        #pragma unroll
        for (int off = 32; off > 0; off >>= 1) {
            s  += __shfl_down(s,  off, 64);
            ss += __shfl_down(ss, off, 64);
        }
        if (lane == 0) { red[wave][0][ni] = s; red[wave][1][ni] = ss; }
    }
    __syncthreads();

    #pragma unroll
    for (int ni = 0; ni < FC1_TILE; ++ni) {
        float s  = red[0][0][ni] + red[1][0][ni];
        float ss = red[0][1][ni] + red[1][1][ni];
        float mean = s * (1.f / B);
        float var  = ss * (1.f / B) - mean * mean;
        float istd = rsqrtf(var + 1e-5f);
        float g  = bn2_g[n0 + ni];
        float be = bn2_b[n0 + ni];
        float scl = g * istd;
        y1n[(n0 + ni) * B + tid] = acc[ni] * scl + (be - mean * scl);
    }
}

// ---------------------------------------------------------------------------
// Kernel 5: fc2.  One block per output neuron k; thread = b.
// ---------------------------------------------------------------------------
__global__ __launch_bounds__(128) void fc2_kernel(
    const float* __restrict__ y1n,             // [500, B]
    const float* __restrict__ fc2_w,           // [200, 500]
    const float* __restrict__ fc2_b,           // [200]
    float* __restrict__ out)                   // [B, 200]
{
    const int k = blockIdx.x;
    const int tid = threadIdx.x;               // = b

    __shared__ float wsm[500];
    for (int i = tid; i < 500; i += 128) wsm[i] = fc2_w[k * 500 + i];
    __syncthreads();

    float acc = fc2_b[k];
    for (int n = 0; n < 500; ++n) acc += y1n[n * B + tid] * wsm[n];
    out[tid * 200 + k] = acc;
}

// ---------------------------------------------------------------------------
extern "C" void kernel_launch(void* const* d_in, const int* in_sizes, int n_in,
                              void* d_out, int out_size, void* d_ws, size_t ws_size,
                              hipStream_t stream) {
    const float* births    = (const float*)d_in[0];
    const float* lifetimes = (const float*)d_in[1];
    const int*   mask      = (const int*)d_in[2];
    const float* centers   = (const float*)d_in[3];
    const float* sharpness = (const float*)d_in[4];
    const float* w1        = (const float*)d_in[5];
    const float* w2        = (const float*)d_in[6];
    const float* l1_w      = (const float*)d_in[7];
    const float* l1_b      = (const float*)d_in[8];
    const float* bn1_g     = (const float*)d_in[9];
    const float* bn1_b     = (const float*)d_in[10];
    const float* l2_w      = (const float*)d_in[11];
    const float* l2_b      = (const float*)d_in[12];
    const float* fc1_w     = (const float*)d_in[13];
    const float* fc1_b     = (const float*)d_in[14];
    const float* bn2_g     = (const float*)d_in[15];
    const float* bn2_b     = (const float*)d_in[16];
    const float* fc2_w     = (const float*)d_in[17];
    const float* fc2_b     = (const float*)d_in[18];
    float* out = (float*)d_out;

    float* ws    = (float*)d_ws;
    float* z     = ws;                            // V*B*J   = 307200
    float* u_pre = ws + 307200;                   // V*B*S2  = 102400
    float* xT    = ws + 307200 + 102400;          // 800*B   = 102400
    float* y1n   = ws + 307200 + 102400 + 102400; // 500*B   = 64000

    slayer_kernel <<<V * B, 128, 0, stream>>>(births, lifetimes, mask, centers, sharpness, z);
    stage12_kernel<<<V * B, 128, 0, stream>>>(z, w1, w2, l1_w, l1_b, u_pre);
    bn1_l2_kernel <<<V, 256, 0, stream>>>(u_pre, bn1_g, bn1_b, l2_w, l2_b, xT);
    fc1_bn2_kernel<<<(500 / FC1_TILE), 128, 0, stream>>>(xT, fc1_w, fc1_b, bn2_g, bn2_b, y1n);
    fc2_kernel    <<<200, 128, 0, stream>>>(y1n, fc2_w, fc2_b, out);
}